// Round 1
// baseline (324.461 us; speedup 1.0000x reference)
//
#include <hip/hip_runtime.h>
#include <hip/hip_bf16.h>

// Shapes fixed by setup_inputs(): b=8, s=4096, h=16, p=64, n=64, L=64.
// Reduction: out[b,h,p,n] = sum_t exp(Total(b,h) - P(b,h,t)) * X[b,t,h,p] * B[b,t,h,n]
// where P = inclusive prefix-sum of A over t, Total = P[s-1]. (Chunked scan telescopes.)

constexpr int Bn = 8;
constexpr int S  = 4096;
constexpr int H  = 16;
constexpr int P  = 64;
constexpr int N  = 64;

constexpr int NCH = 8;         // t-chunks per (b,h) pair
constexpr int TCH = S / NCH;   // 512 timesteps per chunk
constexpr int TB  = 8;         // timesteps staged in LDS per iteration

// ---------------- Kernel 1: per-(b,h) prefix scan of A -> weights ----------------
// W[pair*S + t] = exp(Total - P_inclusive[t]),  pair = bb*H + hh
__global__ __launch_bounds__(256) void scan_weights(
    const float* __restrict__ A, float* __restrict__ W) {
  const int pair = blockIdx.x;         // 0..Bn*H-1
  const int bb = pair / H, hh = pair % H;
  const int tid = threadIdx.x;
  constexpr int TPT = S / 256;         // 16 elements per thread

  float vals[TPT];
  float local = 0.f;
  const int t0 = tid * TPT;
  #pragma unroll
  for (int i = 0; i < TPT; ++i) {
    float a = A[((size_t)bb * S + t0 + i) * H + hh];
    local += a;
    vals[i] = local;                   // inclusive within thread
  }

  __shared__ float sums[256];
  sums[tid] = local;
  __syncthreads();
  // Hillis-Steele inclusive scan over per-thread totals
  for (int off = 1; off < 256; off <<= 1) {
    float v = sums[tid];
    float add = (tid >= off) ? sums[tid - off] : 0.f;
    __syncthreads();
    sums[tid] = v + add;
    __syncthreads();
  }
  const float total = sums[255];
  const float excl  = sums[tid] - local;   // exclusive prefix for this thread

  float* Wp = W + (size_t)pair * S;
  #pragma unroll
  for (int i = 0; i < TPT; ++i) {
    Wp[t0 + i] = __expf(total - (excl + vals[i]));  // exponent <= 0 (A <= 0)
  }
}

// ---------------- Kernel 2: weighted outer-product accumulation ----------------
// One block per (pair, chunk). 256 threads; each owns a 4x4 tile of the 64x64 output.
__global__ __launch_bounds__(256) void outer_accum(
    const float* __restrict__ X, const float* __restrict__ Bm,
    const float* __restrict__ W, float* __restrict__ out) {
  __shared__ float Xs[TB][P];
  __shared__ float Bs[TB][N];

  const int bid  = blockIdx.x;
  const int pair = bid / NCH;
  const int ch   = bid % NCH;
  const int tid  = threadIdx.x;
  const int t_begin = ch * TCH;

  // compute mapping: 16x16 thread grid of 4x4 tiles
  const int n0 = (tid & 15) * 4;
  const int p0 = (tid >> 4) * 4;

  // staging mapping: threads 0..127 load X rows, 128..255 load B rows
  const int lrow = (tid & 127) >> 4;   // 0..7 (staged row)
  const int lcol = (tid & 15) * 4;     // 0..60 (float4 column)
  const bool isB = tid >= 128;

  const int bb = pair / H, hh = pair % H;
  const size_t baseX = ((size_t)bb * S * H + hh) * (size_t)P;  // + t*H*P + col
  const size_t baseB = ((size_t)bb * S * H + hh) * (size_t)N;
  const float* Wp = W + (size_t)pair * S;

  float acc[4][4];
  #pragma unroll
  for (int i = 0; i < 4; ++i)
    #pragma unroll
    for (int j = 0; j < 4; ++j) acc[i][j] = 0.f;

  for (int t0 = t_begin; t0 < t_begin + TCH; t0 += TB) {
    const int t = t0 + lrow;
    if (!isB) {
      const float w = Wp[t];
      const float4 v = *(const float4*)(X + baseX + (size_t)t * H * P + lcol);
      float4 sv; sv.x = v.x * w; sv.y = v.y * w; sv.z = v.z * w; sv.w = v.w * w;
      *(float4*)&Xs[lrow][lcol] = sv;        // pre-scale X by decay weight
    } else {
      *(float4*)&Bs[lrow][lcol] = *(const float4*)(Bm + baseB + (size_t)t * H * N + lcol);
    }
    __syncthreads();

    #pragma unroll
    for (int tt = 0; tt < TB; ++tt) {
      const float4 xv = *(const float4*)&Xs[tt][p0];
      const float4 bv = *(const float4*)&Bs[tt][n0];
      const float xs[4] = {xv.x, xv.y, xv.z, xv.w};
      const float bs[4] = {bv.x, bv.y, bv.z, bv.w};
      #pragma unroll
      for (int i = 0; i < 4; ++i)
        #pragma unroll
        for (int j = 0; j < 4; ++j)
          acc[i][j] = fmaf(xs[i], bs[j], acc[i][j]);
    }
    __syncthreads();
  }

  // combine disjoint t-chunk partials: 8 atomic adds per output element total
  float* outp = out + (size_t)pair * P * N;  // out[b,h,p,n]
  #pragma unroll
  for (int i = 0; i < 4; ++i)
    #pragma unroll
    for (int j = 0; j < 4; ++j)
      atomicAdd(&outp[(size_t)(p0 + i) * N + (n0 + j)], acc[i][j]);
}

extern "C" void kernel_launch(void* const* d_in, const int* in_sizes, int n_in,
                              void* d_out, int out_size, void* d_ws, size_t ws_size,
                              hipStream_t stream) {
  const float* X = (const float*)d_in[0];   // (b, s, h, p)
  const float* A = (const float*)d_in[1];   // (b, s, h)
  const float* B = (const float*)d_in[2];   // (b, s, h, n)
  float* out = (float*)d_out;               // (b, h, p, n)
  float* W   = (float*)d_ws;                // Bn*H*S floats = 2 MB scratch

  // out is poisoned 0xAA before every launch; atomics need zeros
  hipMemsetAsync(d_out, 0, (size_t)out_size * sizeof(float), stream);

  scan_weights<<<Bn * H, 256, 0, stream>>>(A, W);
  outer_accum<<<Bn * H * NCH, 256, 0, stream>>>(X, B, W, out);
}